// Round 2
// baseline (2582.303 us; speedup 1.0000x reference)
//
#include <hip/hip_runtime.h>
#include <hip/hip_cooperative_groups.h>
#include <math.h>

namespace cg = cooperative_groups;

#define B_ 256
#define HID_ 512
#define H_ 8
#define D_ 64
#define FF_ 2048
#define L_ 6
#define EPS_ATTN 1e-6f
#define EPS_LN 1e-5f
#define WT_LAYER 3145728  // u16 elements per layer

typedef unsigned short u16;
typedef __attribute__((ext_vector_type(8))) short short8;
typedef __attribute__((ext_vector_type(4))) float floatx4;

__device__ inline u16 f2bf(float f) {
  union { float f; unsigned u; } un; un.f = f;
  unsigned u = un.u;
  u += 0x7FFFu + ((u >> 16) & 1u);   // RNE truncate to bf16
  return (u16)(u >> 16);
}

// ============================================================================
// Megakernel device pieces (cooperative persistent path)
// ============================================================================

struct MegaParams {
  const int* x; const int* pos;
  const float* S; const float* Z; const float* emb;
  const float* bq; const float* bk; const float* bv; const float* bo;
  const float* b1; const float* b2;
  const float* ln1_g; const float* ln1_b; const float* ln2_g; const float* ln2_b;
  const float* lnf_g; const float* lnf_b;
  const float* Wq; const float* Wk; const float* Wv; const float* Wo;
  const float* W1; const float* W2;
  float* out_h; float* out_S; float* out_Z;
  float* h; u16* hb; u16* attnb; u16* ff1; float* qkv; float* tmpA; float* tmpB;
  u16* wt;
};

// one 64x64 wconvert tile unit; u in [0, 4608)
__device__ __forceinline__ void wconv_unit(
    int u, const float* __restrict__ Wq, const float* __restrict__ Wk,
    const float* __restrict__ Wv, const float* __restrict__ Wo,
    const float* __restrict__ W1, const float* __restrict__ W2,
    u16* __restrict__ wt, char* smem) {
  int l = u / 768, r = u % 768;
  const float* src; int K, N; size_t doff; int tile;
  if (r < 256) {
    int m = r >> 6; tile = r & 63;
    const float* W = m == 0 ? Wq : m == 1 ? Wk : m == 2 ? Wv : Wo;
    src = W + (size_t)l * 262144; K = 512; N = 512; doff = (size_t)m * 262144;
  } else if (r < 512) {
    src = W1 + (size_t)l * 1048576; K = 512; N = 2048; doff = 1048576; tile = r - 256;
  } else {
    src = W2 + (size_t)l * 1048576; K = 2048; N = 512; doff = 2097152; tile = r - 512;
  }
  u16* dst = wt + (size_t)l * WT_LAYER + doff;
  int ntn = N >> 6;
  int tk = tile / ntn, tn = tile % ntn;
  u16 (*sT)[80] = (u16(*)[80])smem;
  int t = threadIdx.x, rr = t >> 2, c = t & 3;
  const float* sp = src + (size_t)(tk * 64 + rr) * N + tn * 64 + c * 16;
#pragma unroll
  for (int i = 0; i < 4; i++) {
    float4 v = *(const float4*)(sp + i * 4);
    int cb = c * 16 + i * 4;
    sT[cb + 0][rr] = f2bf(v.x);
    sT[cb + 1][rr] = f2bf(v.y);
    sT[cb + 2][rr] = f2bf(v.z);
    sT[cb + 3][rr] = f2bf(v.w);
  }
  __syncthreads();
  u16* dp = dst + (size_t)(tn * 64 + rr) * K + tk * 64 + c * 16;
  *(float4*)dp = *(const float4*)&sT[rr][c * 16];
  *(float4*)(dp + 8) = *(const float4*)&sT[rr][c * 16 + 8];
  __syncthreads();  // before next unit reuses sT
}

// 64x64 tile, full-K per wave (4 waves = 4 M-subtiles), fragments direct
// from global. Same lane->element mapping as the verified split-K kernel.
template <int K, int MODE>
__device__ __forceinline__ void gemm_tile(
    int tid, int ntx, const u16* __restrict__ A, const u16* __restrict__ WT,
    const float* __restrict__ b0, const float* __restrict__ b1,
    const float* __restrict__ b2, float* __restrict__ outf,
    u16* __restrict__ outb, int N) {
  int t = threadIdx.x, lane = t & 63, wv = t >> 6;
  int n0 = (tid % ntx) * 64, m0 = (tid / ntx) * 64;
  int lr = lane & 15, lk = lane >> 4;
  const u16* ap = A + (size_t)(m0 + wv * 16 + lr) * K + lk * 8;
  const u16* bp = WT + (size_t)(n0 + lr) * K + lk * 8;
  floatx4 acc[4] = {};
#pragma unroll 2
  for (int it = 0; it < K / 32; ++it) {
    short8 af = *(const short8*)(ap + it * 32);
#pragma unroll
    for (int nt = 0; nt < 4; nt++) {
      short8 bf = *(const short8*)(bp + (size_t)nt * 16 * K + it * 32);
      acc[nt] = __builtin_amdgcn_mfma_f32_16x16x32_bf16(af, bf, acc[nt], 0, 0, 0);
    }
  }
#pragma unroll
  for (int nt = 0; nt < 4; nt++)
#pragma unroll
    for (int rr = 0; rr < 4; rr++) {
      float s = acc[nt][rr];
      int row = m0 + wv * 16 + lk * 4 + rr;
      int col = n0 + nt * 16 + lr;
      if (MODE == 0) {
        int sel = col >> 9, cc = col & 511;
        s += (sel == 0 ? b0 : sel == 1 ? b1 : b2)[cc];
        if (sel < 2) s = s > 0.f ? s + 1.f : expf(s);   // elu(x)+1
        outf[(size_t)sel * (B_ * HID_) + (size_t)row * HID_ + cc] = s;
      } else if (MODE == 1) {
        s += b0[col];
        outf[(size_t)row * N + col] = s;
      } else {
        s += b0[col];
        outb[(size_t)row * N + col] = f2bf(fmaxf(s, 0.f));
      }
    }
}

// one wave handles one (b,h): S update + attn output
__device__ __forceinline__ void state_wave(
    int bh, const float* __restrict__ S_in, const float* __restrict__ Z_in,
    const float* __restrict__ qkv, float* __restrict__ S_out,
    float* __restrict__ Z_out, u16* __restrict__ attnb, float* sh) {
  int lane = threadIdx.x & 63;
  int b = bh >> 3, hh = bh & 7;
  const float* qp = qkv + (size_t)b * HID_ + hh * D_;
  sh[lane] = qp[lane];
  sh[64 + lane] = qp[(size_t)B_ * HID_ + lane];
  sh[128 + lane] = qp[(size_t)2 * B_ * HID_ + lane];
  __syncthreads();   // uniform: all 4 waves execute this together
  int lr = lane & 15, lk = lane >> 4;
  const float4* Sp = (const float4*)(S_in + (size_t)bh * 4096);
  float4* So = (float4*)(S_out + (size_t)bh * 4096);
  float4 vv = *(const float4*)(sh + 128 + lr * 4);
  float4 acc = {0.f, 0.f, 0.f, 0.f};
#pragma unroll 4
  for (int it = 0; it < 16; ++it) {
    int d = it * 4 + lk;
    float kd = sh[64 + d], qd = sh[d];
    float4 s = Sp[d * 16 + lr];
    s.x += kd * vv.x; s.y += kd * vv.y; s.z += kd * vv.z; s.w += kd * vv.w;
    So[d * 16 + lr] = s;
    acc.x += qd * s.x; acc.y += qd * s.y; acc.z += qd * s.z; acc.w += qd * s.w;
  }
#pragma unroll
  for (int m = 16; m <= 32; m <<= 1) {
    acc.x += __shfl_xor(acc.x, m); acc.y += __shfl_xor(acc.y, m);
    acc.z += __shfl_xor(acc.z, m); acc.w += __shfl_xor(acc.w, m);
  }
  float zk = Z_in[(size_t)bh * D_ + lane] + sh[64 + lane];
  Z_out[(size_t)bh * D_ + lane] = zk;
  float dv = sh[lane] * zk;
#pragma unroll
  for (int m = 1; m <= 32; m <<= 1) dv += __shfl_xor(dv, m);
  float den = dv + EPS_ATTN;
  if (lk == 0) {
    ushort4 o;
    o.x = f2bf(acc.x / den); o.y = f2bf(acc.y / den);
    o.z = f2bf(acc.z / den); o.w = f2bf(acc.w / den);
    *(ushort4*)(attnb + (size_t)b * HID_ + hh * D_ + lr * 4) = o;
  }
}

// residual + LayerNorm, one row per block (256 threads, 2 elems/thread)
__device__ __forceinline__ void ln_row(
    int b, const float* __restrict__ x, const float* __restrict__ res,
    const float* __restrict__ g, const float* __restrict__ bb,
    float* __restrict__ out_f, u16* __restrict__ out_b, float* red) {
  int t = threadIdx.x;
  float v0 = x[b * HID_ + t] + (res ? res[b * HID_ + t] : 0.f);
  float v1 = x[b * HID_ + 256 + t] + (res ? res[b * HID_ + 256 + t] : 0.f);
  float s = v0 + v1, ss = v0 * v0 + v1 * v1;
#pragma unroll
  for (int off = 32; off > 0; off >>= 1) {
    s += __shfl_down(s, off);
    ss += __shfl_down(ss, off);
  }
  int w = t >> 6;
  if ((t & 63) == 0) { red[w] = s; red[4 + w] = ss; }
  __syncthreads();
  float S = red[0] + red[1] + red[2] + red[3];
  float SS = red[4] + red[5] + red[6] + red[7];
  float mean = S * (1.f / HID_);
  float var = SS * (1.f / HID_) - mean * mean;
  float inv = rsqrtf(var + EPS_LN);
  float o0 = (v0 - mean) * inv * g[t] + bb[t];
  float o1 = (v1 - mean) * inv * g[256 + t] + bb[256 + t];
  out_f[b * HID_ + t] = o0;
  out_f[b * HID_ + 256 + t] = o1;
  if (out_b) {
    out_b[b * HID_ + t] = f2bf(o0);
    out_b[b * HID_ + 256 + t] = f2bf(o1);
  }
  __syncthreads();  // red reused by later phases
}

__global__ __launch_bounds__(256, 4) void mega(MegaParams p) {
  cg::grid_group grid = cg::this_grid();
  __shared__ __align__(16) char smem[10368];
  int blk = blockIdx.x, t = threadIdx.x, wv = t >> 6;

  // ---- Phase 0: embed (one b per block) + weight convert (all layers) ----
  {
    int tok = p.x[blk];
    float pos = (float)p.pos[0];
    for (int i = t; i < HID_; i += 256) {
      int pair = i >> 1;
      float freq = powf(10000.f, -(float)pair * (1.f / 256.f));
      float ang = pos * freq;
      float pe = (i & 1) ? cosf(ang) : sinf(ang);
      float v = p.emb[(size_t)tok * HID_ + i] + pe;
      p.h[blk * HID_ + i] = v;
      p.hb[blk * HID_ + i] = f2bf(v);
    }
    for (int u = blk; u < 4608; u += 256)
      wconv_unit(u, p.Wq, p.Wk, p.Wv, p.Wo, p.W1, p.W2, p.wt, smem);
  }
  grid.sync();

  for (int l = 0; l < L_; ++l) {
    const u16* wtl = p.wt + (size_t)l * WT_LAYER;
    // P1: QKV GEMM (96 tiles)
    if (blk < 96)
      gemm_tile<512, 0>(blk, 24, p.hb, wtl, p.bq + l * HID_, p.bk + l * HID_,
                        p.bv + l * HID_, p.qkv, nullptr, 1536);
    grid.sync();
    // P2: state update, 8 (b,h) per block (one per wave, 2 rounds)
    {
      float* sh = (float*)smem + wv * 192;
      const float* Si = p.S + (size_t)l * B_ * H_ * D_ * D_;
      const float* Zi = p.Z + (size_t)l * B_ * H_ * D_;
      float* So = p.out_S + (size_t)l * B_ * H_ * D_ * D_;
      float* Zo = p.out_Z + (size_t)l * B_ * H_ * D_;
      for (int j = 0; j < 2; ++j)
        state_wave(blk * 8 + j * 4 + wv, Si, Zi, p.qkv, So, Zo, p.attnb, sh);
    }
    grid.sync();
    // P3: Wo GEMM (32 tiles) -> tmpA f32
    if (blk < 32)
      gemm_tile<512, 1>(blk, 8, p.attnb, wtl + 786432, p.bo + l * HID_,
                        nullptr, nullptr, p.tmpA, nullptr, 512);
    grid.sync();
    // P4: ln1
    ln_row(blk, p.tmpA, p.h, p.ln1_g + l * HID_, p.ln1_b + l * HID_, p.h, p.hb,
           (float*)smem);
    grid.sync();
    // P5: W1 GEMM (128 tiles) -> ff1 bf16 relu
    if (blk < 128)
      gemm_tile<512, 2>(blk, 32, p.hb, wtl + 1048576, p.b1 + l * FF_,
                        nullptr, nullptr, nullptr, p.ff1, 2048);
    grid.sync();
    // P6: W2 GEMM (32 tiles, K=2048) -> tmpB f32
    if (blk < 32)
      gemm_tile<2048, 1>(blk, 8, p.ff1, wtl + 2097152, p.b2 + l * HID_,
                         nullptr, nullptr, p.tmpB, nullptr, 512);
    grid.sync();
    // P7: ln2
    ln_row(blk, p.tmpB, p.h, p.ln2_g + l * HID_, p.ln2_b + l * HID_, p.h, p.hb,
           (float*)smem);
    grid.sync();
  }
  // final LayerNorm -> out_h (f32 only)
  ln_row(blk, p.h, nullptr, p.lnf_g, p.lnf_b, p.out_h, nullptr, (float*)smem);
}

// ============================================================================
// Fallback path: verified R1 multi-dispatch kernels (unchanged)
// ============================================================================

__global__ __launch_bounds__(256) void embed_kernel(
    const int* __restrict__ x, const int* __restrict__ pos,
    const float* __restrict__ emb, float* __restrict__ h, u16* __restrict__ hb) {
  int b = blockIdx.x, t = threadIdx.x;
  int tok = x[b];
  float p = (float)pos[0];
  for (int i = t; i < HID_; i += 256) {
    int pair = i >> 1;
    float freq = powf(10000.f, -(float)pair * (1.f / 256.f));
    float ang = p * freq;
    float pe = (i & 1) ? cosf(ang) : sinf(ang);
    float v = emb[(size_t)tok * HID_ + i] + pe;
    h[b * HID_ + i] = v;
    hb[b * HID_ + i] = f2bf(v);
  }
}

__global__ __launch_bounds__(256) void wconvert(
    const float* __restrict__ Wq, const float* __restrict__ Wk,
    const float* __restrict__ Wv, const float* __restrict__ Wo,
    const float* __restrict__ W1, const float* __restrict__ W2,
    u16* __restrict__ wt, int l0, size_t wt_stride) {
  int l = l0 + blockIdx.z;
  u16* dst = wt + (size_t)blockIdx.z * wt_stride;
  int mat = blockIdx.y;
  const float* src;
  int K, N;
  size_t doff;
  switch (mat) {
    case 0: src = Wq + (size_t)l * 262144; K = 512; N = 512; doff = 0; break;
    case 1: src = Wk + (size_t)l * 262144; K = 512; N = 512; doff = 262144; break;
    case 2: src = Wv + (size_t)l * 262144; K = 512; N = 512; doff = 524288; break;
    case 3: src = Wo + (size_t)l * 262144; K = 512; N = 512; doff = 786432; break;
    case 4: src = W1 + (size_t)l * 1048576; K = 512; N = 2048; doff = 1048576; break;
    default: src = W2 + (size_t)l * 1048576; K = 2048; N = 512; doff = 2097152; break;
  }
  int ntn = N >> 6;
  int ntiles = (K >> 6) * ntn;
  if (blockIdx.x >= ntiles) return;
  int tk = blockIdx.x / ntn, tn = blockIdx.x % ntn;
  __shared__ u16 sT[64][80];
  int t = threadIdx.x;
  int r = t >> 2, c = t & 3;
  const float* sp = src + (size_t)(tk * 64 + r) * N + tn * 64 + c * 16;
#pragma unroll
  for (int i = 0; i < 4; i++) {
    float4 v = *(const float4*)(sp + i * 4);
    int cb = c * 16 + i * 4;
    sT[cb + 0][r] = f2bf(v.x);
    sT[cb + 1][r] = f2bf(v.y);
    sT[cb + 2][r] = f2bf(v.z);
    sT[cb + 3][r] = f2bf(v.w);
  }
  __syncthreads();
  u16* dp = dst + doff + (size_t)(tn * 64 + r) * K + tk * 64 + c * 16;
  *(float4*)dp = *(const float4*)&sT[r][c * 16];
  *(float4*)(dp + 8) = *(const float4*)&sT[r][c * 16 + 8];
}

template <int NIT>
__global__ __launch_bounds__(1024, 1) void gemm_bk(
    const u16* __restrict__ A, const u16* __restrict__ WT,
    const float* __restrict__ b0, const float* __restrict__ b1,
    const float* __restrict__ b2, float* __restrict__ outf,
    u16* __restrict__ outb, int N, int K, int mode) {
  int t = threadIdx.x;
  int lane = t & 63, wv = t >> 6;
  int mg = wv & 3, kg = wv >> 2;
  int m0 = blockIdx.y * 64, n0 = blockIdx.x * 64;
  int KQ = K >> 2;
  const int lr = lane & 15, lk = lane >> 4;
  const u16* ap = A + (size_t)(m0 + mg * 16 + lr) * K + kg * KQ + lk * 8;
  const u16* bp = WT + (size_t)(n0 + lr) * K + kg * KQ + lk * 8;
  floatx4 acc[4] = {};
#pragma unroll 2
  for (int it = 0; it < NIT; ++it) {
    short8 af = *(const short8*)(ap + it * 32);
#pragma unroll
    for (int nt = 0; nt < 4; nt++) {
      short8 bf = *(const short8*)(bp + (size_t)nt * 16 * K + it * 32);
      acc[nt] = __builtin_amdgcn_mfma_f32_16x16x32_bf16(af, bf, acc[nt], 0, 0, 0);
    }
  }
  __shared__ float parts[3][64][68];
  if (kg > 0) {
#pragma unroll
    for (int nt = 0; nt < 4; nt++)
#pragma unroll
      for (int rr = 0; rr < 4; rr++)
        parts[kg - 1][mg * 16 + lk * 4 + rr][nt * 16 + lr] = acc[nt][rr];
  }
  __syncthreads();
  if (kg > 0) return;
#pragma unroll
  for (int nt = 0; nt < 4; nt++) {
#pragma unroll
    for (int rr = 0; rr < 4; rr++) {
      int row = mg * 16 + lk * 4 + rr;
      int col = nt * 16 + lr;
      float s = acc[nt][rr] + parts[0][row][col] + parts[1][row][col] +
                parts[2][row][col];
      int grow = m0 + row, gcol = n0 + col;
      if (mode == 0) {
        int sel = gcol >> 9, cc = gcol & 511;
        s += (sel == 0 ? b0 : sel == 1 ? b1 : b2)[cc];
        if (sel < 2) s = s > 0.f ? s + 1.f : expf(s);
        outf[(size_t)sel * (B_ * HID_) + (size_t)grow * HID_ + cc] = s;
      } else if (mode == 1) {
        s += b0[gcol];
        outf[(size_t)grow * N + gcol] = s;
      } else {
        s += b0[gcol];
        outb[(size_t)grow * N + gcol] = f2bf(fmaxf(s, 0.f));
      }
    }
  }
}

__global__ __launch_bounds__(256) void state_kernel(
    const float* __restrict__ S_in, const float* __restrict__ Z_in,
    const float* __restrict__ qkv, float* __restrict__ S_out,
    float* __restrict__ Z_out, u16* __restrict__ attnb) {
  int bh = blockIdx.x;
  int b = bh >> 3, hh = bh & 7;
  const float* q = qkv + (size_t)b * HID_ + hh * D_;
  const float* k = q + (size_t)B_ * HID_;
  const float* v = q + (size_t)2 * B_ * HID_;
  __shared__ float qs[D_], ks[D_], vs[D_];
  __shared__ float part[16][D_];
  int t = threadIdx.x;
  if (t < D_) { qs[t] = q[t]; ks[t] = k[t]; vs[t] = v[t]; }
  __syncthreads();
  int tm = (t & 15) << 2;
  int rg = t >> 4;
  const float4* Sp = (const float4*)(S_in + (size_t)bh * D_ * D_);
  float4* So = (float4*)(S_out + (size_t)bh * D_ * D_);
  float4 vv = *(const float4*)(vs + tm);
  float4 acc = {0.f, 0.f, 0.f, 0.f};
#pragma unroll
  for (int i = 0; i < 4; i++) {
    int d = rg * 4 + i;
    float kd = ks[d], qd = qs[d];
    float4 s = Sp[(d * D_ + tm) >> 2];
    s.x += kd * vv.x; s.y += kd * vv.y; s.z += kd * vv.z; s.w += kd * vv.w;
    So[(d * D_ + tm) >> 2] = s;
    acc.x += qd * s.x; acc.y += qd * s.y; acc.z += qd * s.z; acc.w += qd * s.w;
  }
  *(float4*)(&part[rg][tm]) = acc;
  __syncthreads();
  if (t < D_) {
    float num = 0.f;
#pragma unroll
    for (int r = 0; r < 16; r++) num += part[r][t];
    float zk = Z_in[(size_t)bh * D_ + t] + ks[t];
    Z_out[(size_t)bh * D_ + t] = zk;
    float dv = qs[t] * zk;
#pragma unroll
    for (int off = 32; off > 0; off >>= 1) dv += __shfl_down(dv, off);
    float den = __shfl(dv, 0) + EPS_ATTN;
    attnb[(size_t)b * HID_ + hh * D_ + t] = f2bf(num / den);
  }
}

__global__ __launch_bounds__(256) void ln_kernel(
    const float* __restrict__ x, const float* __restrict__ res,
    const float* __restrict__ g, const float* __restrict__ bb,
    float* __restrict__ out_f, u16* __restrict__ out_b) {
  int b = blockIdx.x, t = threadIdx.x;
  float v0 = x[b * HID_ + t] + (res ? res[b * HID_ + t] : 0.f);
  float v1 = x[b * HID_ + 256 + t] + (res ? res[b * HID_ + 256 + t] : 0.f);
  float s = v0 + v1, ss = v0 * v0 + v1 * v1;
#pragma unroll
  for (int off = 32; off > 0; off >>= 1) {
    s += __shfl_down(s, off);
    ss += __shfl_down(ss, off);
  }
  __shared__ float rs[4], rss[4];
  int w = t >> 6;
  if ((t & 63) == 0) { rs[w] = s; rss[w] = ss; }
  __syncthreads();
  float S = rs[0] + rs[1] + rs[2] + rs[3];
  float SS = rss[0] + rss[1] + rss[2] + rss[3];
  float mean = S * (1.f / HID_);
  float var = SS * (1.f / HID_) - mean * mean;
  float inv = rsqrtf(var + EPS_LN);
  float o0 = (v0 - mean) * inv * g[t] + bb[t];
  float o1 = (v1 - mean) * inv * g[256 + t] + bb[256 + t];
  out_f[b * HID_ + t] = o0;
  out_f[b * HID_ + 256 + t] = o1;
  if (out_b) {
    out_b[b * HID_ + t] = f2bf(o0);
    out_b[b * HID_ + 256 + t] = f2bf(o1);
  }
}

// ============================================================================

extern "C" void kernel_launch(void* const* d_in, const int* in_sizes, int n_in,
                              void* d_out, int out_size, void* d_ws, size_t ws_size,
                              hipStream_t stream) {
  const int* x = (const int*)d_in[0];
  const int* pos = (const int*)d_in[1];
  const float* S = (const float*)d_in[2];
  const float* Z = (const float*)d_in[3];
  const float* emb = (const float*)d_in[4];
  const float* Wq = (const float*)d_in[5];
  const float* bq = (const float*)d_in[6];
  const float* Wk = (const float*)d_in[7];
  const float* bk = (const float*)d_in[8];
  const float* Wv = (const float*)d_in[9];
  const float* bv = (const float*)d_in[10];
  const float* Wo = (const float*)d_in[11];
  const float* bo = (const float*)d_in[12];
  const float* W1 = (const float*)d_in[13];
  const float* b1 = (const float*)d_in[14];
  const float* W2 = (const float*)d_in[15];
  const float* b2 = (const float*)d_in[16];
  const float* ln1_g = (const float*)d_in[17];
  const float* ln1_b = (const float*)d_in[18];
  const float* ln2_g = (const float*)d_in[19];
  const float* ln2_b = (const float*)d_in[20];
  const float* lnf_g = (const float*)d_in[21];
  const float* lnf_b = (const float*)d_in[22];

  float* out_h = (float*)d_out;
  float* out_S = out_h + (size_t)B_ * HID_;
  float* out_Z = out_S + (size_t)L_ * B_ * H_ * D_ * D_;

  char* w = (char*)d_ws;
  float* h     = (float*)(w + 0);          // 512 KB
  u16*   hb    = (u16*)(w + 524288);       // 256 KB
  u16*   attnb = (u16*)(w + 786432);       // 256 KB
  u16*   ff1   = (u16*)(w + 1048576);      // 1 MB
  float* qkv   = (float*)(w + 2097152);    // 1.5 MB
  float* tmpA  = (float*)(w + 3670016);    // 512 KB
  float* tmpB  = (float*)(w + 4194304);    // 512 KB
  u16*   wt    = (u16*)(w + 13109248);     // 6.29 MB/layer
  bool bigws = ws_size >= (size_t)13109248 + (size_t)WT_LAYER * 2 * L_;

  // ---- try the cooperative persistent megakernel ----
  int coop = 0;
  {
    int dev = 0;
    if (hipGetDevice(&dev) == hipSuccess)
      hipDeviceGetAttribute(&coop, hipDeviceAttributeCooperativeLaunch, dev);
  }
  if (coop && bigws) {
    MegaParams mp;
    mp.x = x; mp.pos = pos; mp.S = S; mp.Z = Z; mp.emb = emb;
    mp.bq = bq; mp.bk = bk; mp.bv = bv; mp.bo = bo; mp.b1 = b1; mp.b2 = b2;
    mp.ln1_g = ln1_g; mp.ln1_b = ln1_b; mp.ln2_g = ln2_g; mp.ln2_b = ln2_b;
    mp.lnf_g = lnf_g; mp.lnf_b = lnf_b;
    mp.Wq = Wq; mp.Wk = Wk; mp.Wv = Wv; mp.Wo = Wo; mp.W1 = W1; mp.W2 = W2;
    mp.out_h = out_h; mp.out_S = out_S; mp.out_Z = out_Z;
    mp.h = h; mp.hb = hb; mp.attnb = attnb; mp.ff1 = ff1; mp.qkv = qkv;
    mp.tmpA = tmpA; mp.tmpB = tmpB; mp.wt = wt;
    void* kargs[] = {&mp};
    hipError_t e = hipLaunchCooperativeKernel((const void*)mega, dim3(256),
                                              dim3(256), kargs, 0, stream);
    if (e == hipSuccess) return;
  }

  // ---- fallback: verified R1 multi-dispatch path ----
  embed_kernel<<<B_, 256, 0, stream>>>(x, pos, emb, h, hb);
  if (bigws)
    wconvert<<<dim3(256, 6, L_), 256, 0, stream>>>(Wq, Wk, Wv, Wo, W1, W2,
                                                   wt, 0, WT_LAYER);
  for (int l = 0; l < L_; l++) {
    u16* wtl = bigws ? wt + (size_t)l * WT_LAYER : wt;
    if (!bigws)
      wconvert<<<dim3(256, 6, 1), 256, 0, stream>>>(Wq, Wk, Wv, Wo, W1, W2,
                                                    wtl, l, 0);
    gemm_bk<4><<<dim3(24, 4), 1024, 0, stream>>>(
        hb, wtl, bq + l * HID_, bk + l * HID_, bv + l * HID_,
        qkv, nullptr, 1536, 512, 0);
    state_kernel<<<B_ * H_, 256, 0, stream>>>(
        S + (size_t)l * B_ * H_ * D_ * D_, Z + (size_t)l * B_ * H_ * D_, qkv,
        out_S + (size_t)l * B_ * H_ * D_ * D_, out_Z + (size_t)l * B_ * H_ * D_,
        attnb);
    gemm_bk<4><<<dim3(8, 4), 1024, 0, stream>>>(
        attnb, wtl + 786432, bo + l * HID_, nullptr, nullptr,
        tmpA, nullptr, 512, 512, 1);
    ln_kernel<<<B_, 256, 0, stream>>>(tmpA, h, ln1_g + l * HID_, ln1_b + l * HID_, h, hb);
    gemm_bk<4><<<dim3(32, 4), 1024, 0, stream>>>(
        hb, wtl + 1048576, b1 + l * FF_, nullptr, nullptr,
        nullptr, ff1, 2048, 512, 2);
    gemm_bk<16><<<dim3(8, 4), 1024, 0, stream>>>(
        ff1, wtl + 2097152, b2 + l * HID_, nullptr, nullptr,
        tmpB, nullptr, 512, 2048, 1);
    ln_kernel<<<B_, 256, 0, stream>>>(tmpB, h, ln2_g + l * HID_, ln2_b + l * HID_, h, hb);
  }
  ln_kernel<<<B_, 256, 0, stream>>>(h, nullptr, lnf_g, lnf_b, out_h, nullptr);
}

// Round 3
// 2209.303 us; speedup vs baseline: 1.1688x; 1.1688x over previous
//
#include <hip/hip_runtime.h>
#include <hip/hip_cooperative_groups.h>
#include <math.h>

namespace cg = cooperative_groups;

#define B_ 256
#define HID_ 512
#define H_ 8
#define D_ 64
#define FF_ 2048
#define L_ 6
#define EPS_ATTN 1e-6f
#define EPS_LN 1e-5f
#define WT_LAYER 3145728  // u16 elements per layer

typedef unsigned short u16;
typedef __attribute__((ext_vector_type(8))) short short8;
typedef __attribute__((ext_vector_type(4))) float floatx4;

__device__ inline u16 f2bf(float f) {
  union { float f; unsigned u; } un; un.f = f;
  unsigned u = un.u;
  u += 0x7FFFu + ((u >> 16) & 1u);   // RNE truncate to bf16
  return (u16)(u >> 16);
}

// ============================================================================
// Megakernel v2: 256 blocks x 1024 threads (16 waves/CU), cooperative.
// Phase bodies are the R1-verified kernels re-hosted as device functions.
// ============================================================================

struct MegaParams {
  const int* x; const int* pos;
  const float* S; const float* Z; const float* emb;
  const float* bq; const float* bk; const float* bv; const float* bo;
  const float* b1; const float* b2;
  const float* ln1_g; const float* ln1_b; const float* ln2_g; const float* ln2_b;
  const float* lnf_g; const float* lnf_b;
  const float* Wq; const float* Wk; const float* Wv; const float* Wo;
  const float* W1; const float* W2;
  float* out_h; float* out_S; float* out_Z;
  float* h; u16* hb; u16* attnb; u16* ff1; float* qkv; float* tmpA; float* tmpB;
  u16* wt;
};

// --- one 64x64 wconvert tile, 1024 threads: 1 float4 load + 1 ushort4 store
__device__ __forceinline__ void wconv_unit1k(int u, const MegaParams& p,
                                             char* smem) {
  int l = u / 768, r = u % 768;
  const float* src; int K, N; size_t doff; int tile;
  if (r < 256) {
    int m = r >> 6; tile = r & 63;
    const float* W = m == 0 ? p.Wq : m == 1 ? p.Wk : m == 2 ? p.Wv : p.Wo;
    src = W + (size_t)l * 262144; K = 512; N = 512; doff = (size_t)m * 262144;
  } else if (r < 512) {
    src = p.W1 + (size_t)l * 1048576; K = 512; N = 2048; doff = 1048576;
    tile = r - 256;
  } else {
    src = p.W2 + (size_t)l * 1048576; K = 2048; N = 512; doff = 2097152;
    tile = r - 512;
  }
  u16* dst = p.wt + (size_t)l * WT_LAYER + doff;
  int ntn = N >> 6, tk = tile / ntn, tn = tile % ntn;
  u16 (*sT)[68] = (u16(*)[68])smem;   // pad 68: rows 136B (8B-aligned), ~2-4 way
  int t = threadIdx.x, rr = t >> 4, c = t & 15;
  float4 v = *(const float4*)(src + (size_t)(tk * 64 + rr) * N + tn * 64 + c * 4);
  sT[c * 4 + 0][rr] = f2bf(v.x);
  sT[c * 4 + 1][rr] = f2bf(v.y);
  sT[c * 4 + 2][rr] = f2bf(v.z);
  sT[c * 4 + 3][rr] = f2bf(v.w);
  __syncthreads();
  *(ushort4*)(dst + (size_t)(tn * 64 + rr) * K + tk * 64 + c * 4) =
      *(const ushort4*)&sT[rr][c * 4];
  __syncthreads();  // before next unit reuses sT
}

// --- R1 gemm_bk body as a device function (16 waves: 4M x 4K split-K).
// mode 0: QKV (N=1536 -> qkv[3][256][512], elu+1 on q,k); 1: f32+bias;
// 2: bf16+bias+relu. kg>0 waves skip epilogue (no early return).
template <int NIT, int MODE>
__device__ __forceinline__ void gemm_unit(
    int tid, int ntx, const u16* __restrict__ A, const u16* __restrict__ WT,
    const float* __restrict__ b0, const float* __restrict__ b1,
    const float* __restrict__ b2, float* __restrict__ outf,
    u16* __restrict__ outb, int N, int K, char* smem) {
  int t = threadIdx.x, lane = t & 63, wv = t >> 6;
  int mg = wv & 3, kg = wv >> 2;
  int m0 = (tid / ntx) * 64, n0 = (tid % ntx) * 64;
  int KQ = K >> 2;                    // == NIT*32
  int lr = lane & 15, lk = lane >> 4;
  const u16* ap = A + (size_t)(m0 + mg * 16 + lr) * K + kg * KQ + lk * 8;
  const u16* bp = WT + (size_t)(n0 + lr) * K + kg * KQ + lk * 8;
  floatx4 acc[4] = {};
#pragma unroll 2
  for (int it = 0; it < NIT; ++it) {
    short8 af = *(const short8*)(ap + it * 32);
#pragma unroll
    for (int nt = 0; nt < 4; nt++) {
      short8 bf = *(const short8*)(bp + (size_t)nt * 16 * K + it * 32);
      acc[nt] = __builtin_amdgcn_mfma_f32_16x16x32_bf16(af, bf, acc[nt], 0, 0, 0);
    }
  }
  float (*parts)[64][68] = (float(*)[64][68])smem;
  if (kg > 0) {
#pragma unroll
    for (int nt = 0; nt < 4; nt++)
#pragma unroll
      for (int rr = 0; rr < 4; rr++)
        parts[kg - 1][mg * 16 + lk * 4 + rr][nt * 16 + lr] = acc[nt][rr];
  }
  __syncthreads();
  if (kg == 0) {
#pragma unroll
    for (int nt = 0; nt < 4; nt++) {
#pragma unroll
      for (int rr = 0; rr < 4; rr++) {
        int row = mg * 16 + lk * 4 + rr;
        int col = nt * 16 + lr;
        float s = acc[nt][rr] + parts[0][row][col] + parts[1][row][col] +
                  parts[2][row][col];
        int grow = m0 + row, gcol = n0 + col;
        if (MODE == 0) {
          int sel = gcol >> 9, cc = gcol & 511;
          s += (sel == 0 ? b0 : sel == 1 ? b1 : b2)[cc];
          if (sel < 2) s = s > 0.f ? s + 1.f : expf(s);   // elu(x)+1
          outf[(size_t)sel * (B_ * HID_) + (size_t)grow * HID_ + cc] = s;
        } else if (MODE == 1) {
          s += b0[gcol];
          outf[(size_t)grow * N + gcol] = s;
        } else {
          s += b0[gcol];
          outb[(size_t)grow * N + gcol] = f2bf(fmaxf(s, 0.f));
        }
      }
    }
  }
}

// --- one (b,h) state update per wave, pure shuffles (no LDS, no block sync)
__device__ __forceinline__ void state_unit(
    int bh, const float* __restrict__ S_in, const float* __restrict__ Z_in,
    const float* __restrict__ qkv, float* __restrict__ S_out,
    float* __restrict__ Z_out, u16* __restrict__ attnb) {
  int lane = threadIdx.x & 63;
  int b = bh >> 3, hh = bh & 7;
  const float* qp = qkv + (size_t)b * HID_ + hh * D_;
  float qv = qp[lane];
  float kv = qp[(size_t)B_ * HID_ + lane];
  float vvs = qp[(size_t)2 * B_ * HID_ + lane];
  int lr = lane & 15, lk = lane >> 4;
  float4 vv;
  vv.x = __shfl(vvs, lr * 4 + 0); vv.y = __shfl(vvs, lr * 4 + 1);
  vv.z = __shfl(vvs, lr * 4 + 2); vv.w = __shfl(vvs, lr * 4 + 3);
  const float4* Sp = (const float4*)(S_in + (size_t)bh * 4096);
  float4* So = (float4*)(S_out + (size_t)bh * 4096);
  float4 acc = {0.f, 0.f, 0.f, 0.f};
#pragma unroll 8
  for (int it = 0; it < 16; ++it) {
    int d = it * 4 + lk;
    float kd = __shfl(kv, d), qd = __shfl(qv, d);
    float4 s = Sp[d * 16 + lr];
    s.x += kd * vv.x; s.y += kd * vv.y; s.z += kd * vv.z; s.w += kd * vv.w;
    So[d * 16 + lr] = s;
    acc.x += qd * s.x; acc.y += qd * s.y; acc.z += qd * s.z; acc.w += qd * s.w;
  }
#pragma unroll
  for (int m = 16; m <= 32; m <<= 1) {
    acc.x += __shfl_xor(acc.x, m); acc.y += __shfl_xor(acc.y, m);
    acc.z += __shfl_xor(acc.z, m); acc.w += __shfl_xor(acc.w, m);
  }
  float zk = Z_in[(size_t)bh * D_ + lane] + kv;
  Z_out[(size_t)bh * D_ + lane] = zk;
  float dv = qv * zk;
#pragma unroll
  for (int m = 1; m <= 32; m <<= 1) dv += __shfl_xor(dv, m);
  float den = dv + EPS_ATTN;
  if (lk == 0) {
    ushort4 o;
    o.x = f2bf(acc.x / den); o.y = f2bf(acc.y / den);
    o.z = f2bf(acc.z / den); o.w = f2bf(acc.w / den);
    *(ushort4*)(attnb + (size_t)b * HID_ + hh * D_ + lr * 4) = o;
  }
}

// --- residual + LayerNorm, one row per block, 1024 threads (512 active)
__device__ __forceinline__ void ln_unit(
    int row, const float* __restrict__ x, const float* __restrict__ res,
    const float* __restrict__ g, const float* __restrict__ bb,
    float* __restrict__ out_f, u16* __restrict__ out_b, char* smem) {
  int t = threadIdx.x;
  float v = 0.f;
  if (t < HID_) v = x[row * HID_ + t] + (res ? res[row * HID_ + t] : 0.f);
  float s = v, ss = v * v;
#pragma unroll
  for (int off = 32; off > 0; off >>= 1) {
    s += __shfl_down(s, off);
    ss += __shfl_down(ss, off);
  }
  float* red = (float*)smem;
  int w = t >> 6;
  if ((t & 63) == 0) { red[w] = s; red[16 + w] = ss; }
  __syncthreads();
  float S = 0.f, SS = 0.f;
#pragma unroll
  for (int i = 0; i < 16; i++) { S += red[i]; SS += red[16 + i]; }
  float mean = S * (1.f / HID_);
  float var = SS * (1.f / HID_) - mean * mean;
  float inv = rsqrtf(var + EPS_LN);
  if (t < HID_) {
    float o = (v - mean) * inv * g[t] + bb[t];
    out_f[row * HID_ + t] = o;
    if (out_b) out_b[row * HID_ + t] = f2bf(o);
  }
  __syncthreads();   // red reused by later phases
}

__global__ __launch_bounds__(1024, 4) void mega(MegaParams p) {
  cg::grid_group grid = cg::this_grid();
  __shared__ __align__(16) char smem[52224];   // parts[3][64][68] f32
  int blk = blockIdx.x, t = threadIdx.x, wv = t >> 6;

  // ---- P0: embed (one row per block) + weight convert (all layers) ----
  {
    int tok = p.x[blk];
    float pos = (float)p.pos[0];
    if (t < HID_) {
      int pair = t >> 1;
      float freq = powf(10000.f, -(float)pair * (1.f / 256.f));
      float ang = pos * freq;
      float pe = (t & 1) ? cosf(ang) : sinf(ang);
      float v = p.emb[(size_t)tok * HID_ + t] + pe;
      p.h[blk * HID_ + t] = v;
      p.hb[blk * HID_ + t] = f2bf(v);
    }
    for (int u = blk; u < 4608; u += 256)   // 18 units per block, 1024-thr each
      wconv_unit1k(u, p, smem);
  }
  grid.sync();

  for (int l = 0; l < L_; ++l) {
    const u16* wtl = p.wt + (size_t)l * WT_LAYER;
    // P1: QKV GEMM (96 tiles)
    if (blk < 96)
      gemm_unit<4, 0>(blk, 24, p.hb, wtl, p.bq + l * HID_, p.bk + l * HID_,
                      p.bv + l * HID_, p.qkv, nullptr, 1536, 512, smem);
    grid.sync();
    // P2: state update, 8 (b,h) per block, one per wave (waves 0..7)
    if (wv < 8)
      state_unit(blk * 8 + wv, p.S + (size_t)l * B_ * H_ * D_ * D_,
                 p.Z + (size_t)l * B_ * H_ * D_, p.qkv,
                 p.out_S + (size_t)l * B_ * H_ * D_ * D_,
                 p.out_Z + (size_t)l * B_ * H_ * D_, p.attnb);
    grid.sync();
    // P3: Wo GEMM (32 tiles) -> tmpA f32
    if (blk < 32)
      gemm_unit<4, 1>(blk, 8, p.attnb, wtl + 786432, p.bo + l * HID_,
                      nullptr, nullptr, p.tmpA, nullptr, 512, 512, smem);
    grid.sync();
    // P4: ln1
    ln_unit(blk, p.tmpA, p.h, p.ln1_g + l * HID_, p.ln1_b + l * HID_, p.h,
            p.hb, smem);
    grid.sync();
    // P5: W1 GEMM (128 tiles) -> ff1 bf16 relu
    if (blk < 128)
      gemm_unit<4, 2>(blk, 32, p.hb, wtl + 1048576, p.b1 + l * FF_,
                      nullptr, nullptr, nullptr, p.ff1, 2048, 512, smem);
    grid.sync();
    // P6: W2 GEMM (32 tiles, K=2048) -> tmpB f32
    if (blk < 32)
      gemm_unit<16, 1>(blk, 8, p.ff1, wtl + 2097152, p.b2 + l * HID_,
                       nullptr, nullptr, p.tmpB, nullptr, 512, 2048, smem);
    grid.sync();
    // P7: ln2
    ln_unit(blk, p.tmpB, p.h, p.ln2_g + l * HID_, p.ln2_b + l * HID_, p.h,
            p.hb, smem);
    grid.sync();
  }
  // final LayerNorm -> out_h (f32 only)
  ln_unit(blk, p.h, nullptr, p.lnf_g, p.lnf_b, p.out_h, nullptr, smem);
}

// ============================================================================
// Fallback path: verified R1 multi-dispatch kernels (unchanged)
// ============================================================================

__global__ __launch_bounds__(256) void embed_kernel(
    const int* __restrict__ x, const int* __restrict__ pos,
    const float* __restrict__ emb, float* __restrict__ h, u16* __restrict__ hb) {
  int b = blockIdx.x, t = threadIdx.x;
  int tok = x[b];
  float p = (float)pos[0];
  for (int i = t; i < HID_; i += 256) {
    int pair = i >> 1;
    float freq = powf(10000.f, -(float)pair * (1.f / 256.f));
    float ang = p * freq;
    float pe = (i & 1) ? cosf(ang) : sinf(ang);
    float v = emb[(size_t)tok * HID_ + i] + pe;
    h[b * HID_ + i] = v;
    hb[b * HID_ + i] = f2bf(v);
  }
}

__global__ __launch_bounds__(256) void wconvert(
    const float* __restrict__ Wq, const float* __restrict__ Wk,
    const float* __restrict__ Wv, const float* __restrict__ Wo,
    const float* __restrict__ W1, const float* __restrict__ W2,
    u16* __restrict__ wt, int l0, size_t wt_stride) {
  int l = l0 + blockIdx.z;
  u16* dst = wt + (size_t)blockIdx.z * wt_stride;
  int mat = blockIdx.y;
  const float* src;
  int K, N;
  size_t doff;
  switch (mat) {
    case 0: src = Wq + (size_t)l * 262144; K = 512; N = 512; doff = 0; break;
    case 1: src = Wk + (size_t)l * 262144; K = 512; N = 512; doff = 262144; break;
    case 2: src = Wv + (size_t)l * 262144; K = 512; N = 512; doff = 524288; break;
    case 3: src = Wo + (size_t)l * 262144; K = 512; N = 512; doff = 786432; break;
    case 4: src = W1 + (size_t)l * 1048576; K = 512; N = 2048; doff = 1048576; break;
    default: src = W2 + (size_t)l * 1048576; K = 2048; N = 512; doff = 2097152; break;
  }
  int ntn = N >> 6;
  int ntiles = (K >> 6) * ntn;
  if (blockIdx.x >= ntiles) return;
  int tk = blockIdx.x / ntn, tn = blockIdx.x % ntn;
  __shared__ u16 sT[64][80];
  int t = threadIdx.x;
  int r = t >> 2, c = t & 3;
  const float* sp = src + (size_t)(tk * 64 + r) * N + tn * 64 + c * 16;
#pragma unroll
  for (int i = 0; i < 4; i++) {
    float4 v = *(const float4*)(sp + i * 4);
    int cb = c * 16 + i * 4;
    sT[cb + 0][r] = f2bf(v.x);
    sT[cb + 1][r] = f2bf(v.y);
    sT[cb + 2][r] = f2bf(v.z);
    sT[cb + 3][r] = f2bf(v.w);
  }
  __syncthreads();
  u16* dp = dst + doff + (size_t)(tn * 64 + r) * K + tk * 64 + c * 16;
  *(float4*)dp = *(const float4*)&sT[r][c * 16];
  *(float4*)(dp + 8) = *(const float4*)&sT[r][c * 16 + 8];
}

template <int NIT>
__global__ __launch_bounds__(1024, 1) void gemm_bk(
    const u16* __restrict__ A, const u16* __restrict__ WT,
    const float* __restrict__ b0, const float* __restrict__ b1,
    const float* __restrict__ b2, float* __restrict__ outf,
    u16* __restrict__ outb, int N, int K, int mode) {
  int t = threadIdx.x;
  int lane = t & 63, wv = t >> 6;
  int mg = wv & 3, kg = wv >> 2;
  int m0 = blockIdx.y * 64, n0 = blockIdx.x * 64;
  int KQ = K >> 2;
  const int lr = lane & 15, lk = lane >> 4;
  const u16* ap = A + (size_t)(m0 + mg * 16 + lr) * K + kg * KQ + lk * 8;
  const u16* bp = WT + (size_t)(n0 + lr) * K + kg * KQ + lk * 8;
  floatx4 acc[4] = {};
#pragma unroll 2
  for (int it = 0; it < NIT; ++it) {
    short8 af = *(const short8*)(ap + it * 32);
#pragma unroll
    for (int nt = 0; nt < 4; nt++) {
      short8 bf = *(const short8*)(bp + (size_t)nt * 16 * K + it * 32);
      acc[nt] = __builtin_amdgcn_mfma_f32_16x16x32_bf16(af, bf, acc[nt], 0, 0, 0);
    }
  }
  __shared__ float parts[3][64][68];
  if (kg > 0) {
#pragma unroll
    for (int nt = 0; nt < 4; nt++)
#pragma unroll
      for (int rr = 0; rr < 4; rr++)
        parts[kg - 1][mg * 16 + lk * 4 + rr][nt * 16 + lr] = acc[nt][rr];
  }
  __syncthreads();
  if (kg > 0) return;
#pragma unroll
  for (int nt = 0; nt < 4; nt++) {
#pragma unroll
    for (int rr = 0; rr < 4; rr++) {
      int row = mg * 16 + lk * 4 + rr;
      int col = nt * 16 + lr;
      float s = acc[nt][rr] + parts[0][row][col] + parts[1][row][col] +
                parts[2][row][col];
      int grow = m0 + row, gcol = n0 + col;
      if (mode == 0) {
        int sel = gcol >> 9, cc = gcol & 511;
        s += (sel == 0 ? b0 : sel == 1 ? b1 : b2)[cc];
        if (sel < 2) s = s > 0.f ? s + 1.f : expf(s);
        outf[(size_t)sel * (B_ * HID_) + (size_t)grow * HID_ + cc] = s;
      } else if (mode == 1) {
        s += b0[gcol];
        outf[(size_t)grow * N + gcol] = s;
      } else {
        s += b0[gcol];
        outb[(size_t)grow * N + gcol] = f2bf(fmaxf(s, 0.f));
      }
    }
  }
}

__global__ __launch_bounds__(256) void state_kernel(
    const float* __restrict__ S_in, const float* __restrict__ Z_in,
    const float* __restrict__ qkv, float* __restrict__ S_out,
    float* __restrict__ Z_out, u16* __restrict__ attnb) {
  int bh = blockIdx.x;
  int b = bh >> 3, hh = bh & 7;
  const float* q = qkv + (size_t)b * HID_ + hh * D_;
  const float* k = q + (size_t)B_ * HID_;
  const float* v = q + (size_t)2 * B_ * HID_;
  __shared__ float qs[D_], ks[D_], vs[D_];
  __shared__ float part[16][D_];
  int t = threadIdx.x;
  if (t < D_) { qs[t] = q[t]; ks[t] = k[t]; vs[t] = v[t]; }
  __syncthreads();
  int tm = (t & 15) << 2;
  int rg = t >> 4;
  const float4* Sp = (const float4*)(S_in + (size_t)bh * D_ * D_);
  float4* So = (float4*)(S_out + (size_t)bh * D_ * D_);
  float4 vv = *(const float4*)(vs + tm);
  float4 acc = {0.f, 0.f, 0.f, 0.f};
#pragma unroll
  for (int i = 0; i < 4; i++) {
    int d = rg * 4 + i;
    float kd = ks[d], qd = qs[d];
    float4 s = Sp[(d * D_ + tm) >> 2];
    s.x += kd * vv.x; s.y += kd * vv.y; s.z += kd * vv.z; s.w += kd * vv.w;
    So[(d * D_ + tm) >> 2] = s;
    acc.x += qd * s.x; acc.y += qd * s.y; acc.z += qd * s.z; acc.w += qd * s.w;
  }
  *(float4*)(&part[rg][tm]) = acc;
  __syncthreads();
  if (t < D_) {
    float num = 0.f;
#pragma unroll
    for (int r = 0; r < 16; r++) num += part[r][t];
    float zk = Z_in[(size_t)bh * D_ + t] + ks[t];
    Z_out[(size_t)bh * D_ + t] = zk;
    float dv = qs[t] * zk;
#pragma unroll
    for (int off = 32; off > 0; off >>= 1) dv += __shfl_down(dv, off);
    float den = __shfl(dv, 0) + EPS_ATTN;
    attnb[(size_t)b * HID_ + hh * D_ + t] = f2bf(num / den);
  }
}

__global__ __launch_bounds__(256) void ln_kernel(
    const float* __restrict__ x, const float* __restrict__ res,
    const float* __restrict__ g, const float* __restrict__ bb,
    float* __restrict__ out_f, u16* __restrict__ out_b) {
  int b = blockIdx.x, t = threadIdx.x;
  float v0 = x[b * HID_ + t] + (res ? res[b * HID_ + t] : 0.f);
  float v1 = x[b * HID_ + 256 + t] + (res ? res[b * HID_ + 256 + t] : 0.f);
  float s = v0 + v1, ss = v0 * v0 + v1 * v1;
#pragma unroll
  for (int off = 32; off > 0; off >>= 1) {
    s += __shfl_down(s, off);
    ss += __shfl_down(ss, off);
  }
  __shared__ float rs[4], rss[4];
  int w = t >> 6;
  if ((t & 63) == 0) { rs[w] = s; rss[w] = ss; }
  __syncthreads();
  float S = rs[0] + rs[1] + rs[2] + rs[3];
  float SS = rss[0] + rss[1] + rss[2] + rss[3];
  float mean = S * (1.f / HID_);
  float var = SS * (1.f / HID_) - mean * mean;
  float inv = rsqrtf(var + EPS_LN);
  float o0 = (v0 - mean) * inv * g[t] + bb[t];
  float o1 = (v1 - mean) * inv * g[256 + t] + bb[256 + t];
  out_f[b * HID_ + t] = o0;
  out_f[b * HID_ + 256 + t] = o1;
  if (out_b) {
    out_b[b * HID_ + t] = f2bf(o0);
    out_b[b * HID_ + 256 + t] = f2bf(o1);
  }
}

// ============================================================================

extern "C" void kernel_launch(void* const* d_in, const int* in_sizes, int n_in,
                              void* d_out, int out_size, void* d_ws, size_t ws_size,
                              hipStream_t stream) {
  const int* x = (const int*)d_in[0];
  const int* pos = (const int*)d_in[1];
  const float* S = (const float*)d_in[2];
  const float* Z = (const float*)d_in[3];
  const float* emb = (const float*)d_in[4];
  const float* Wq = (const float*)d_in[5];
  const float* bq = (const float*)d_in[6];
  const float* Wk = (const float*)d_in[7];
  const float* bk = (const float*)d_in[8];
  const float* Wv = (const float*)d_in[9];
  const float* bv = (const float*)d_in[10];
  const float* Wo = (const float*)d_in[11];
  const float* bo = (const float*)d_in[12];
  const float* W1 = (const float*)d_in[13];
  const float* b1 = (const float*)d_in[14];
  const float* W2 = (const float*)d_in[15];
  const float* b2 = (const float*)d_in[16];
  const float* ln1_g = (const float*)d_in[17];
  const float* ln1_b = (const float*)d_in[18];
  const float* ln2_g = (const float*)d_in[19];
  const float* ln2_b = (const float*)d_in[20];
  const float* lnf_g = (const float*)d_in[21];
  const float* lnf_b = (const float*)d_in[22];

  float* out_h = (float*)d_out;
  float* out_S = out_h + (size_t)B_ * HID_;
  float* out_Z = out_S + (size_t)L_ * B_ * H_ * D_ * D_;

  char* w = (char*)d_ws;
  float* h     = (float*)(w + 0);          // 512 KB
  u16*   hb    = (u16*)(w + 524288);       // 256 KB
  u16*   attnb = (u16*)(w + 786432);       // 256 KB
  u16*   ff1   = (u16*)(w + 1048576);      // 1 MB
  float* qkv   = (float*)(w + 2097152);    // 1.5 MB
  float* tmpA  = (float*)(w + 3670016);    // 512 KB
  float* tmpB  = (float*)(w + 4194304);    // 512 KB
  u16*   wt    = (u16*)(w + 13109248);     // 6.29 MB/layer
  bool bigws = ws_size >= (size_t)13109248 + (size_t)WT_LAYER * 2 * L_;

  // ---- try the cooperative persistent megakernel (1024-thr blocks) ----
  int coop = 0;
  {
    int dev = 0;
    if (hipGetDevice(&dev) == hipSuccess)
      hipDeviceGetAttribute(&coop, hipDeviceAttributeCooperativeLaunch, dev);
  }
  if (coop && bigws) {
    MegaParams mp;
    mp.x = x; mp.pos = pos; mp.S = S; mp.Z = Z; mp.emb = emb;
    mp.bq = bq; mp.bk = bk; mp.bv = bv; mp.bo = bo; mp.b1 = b1; mp.b2 = b2;
    mp.ln1_g = ln1_g; mp.ln1_b = ln1_b; mp.ln2_g = ln2_g; mp.ln2_b = ln2_b;
    mp.lnf_g = lnf_g; mp.lnf_b = lnf_b;
    mp.Wq = Wq; mp.Wk = Wk; mp.Wv = Wv; mp.Wo = Wo; mp.W1 = W1; mp.W2 = W2;
    mp.out_h = out_h; mp.out_S = out_S; mp.out_Z = out_Z;
    mp.h = h; mp.hb = hb; mp.attnb = attnb; mp.ff1 = ff1; mp.qkv = qkv;
    mp.tmpA = tmpA; mp.tmpB = tmpB; mp.wt = wt;
    void* kargs[] = {&mp};
    hipError_t e = hipLaunchCooperativeKernel((const void*)mega, dim3(256),
                                              dim3(1024), kargs, 0, stream);
    if (e == hipSuccess) return;
  }

  // ---- fallback: verified R1 multi-dispatch path ----
  embed_kernel<<<B_, 256, 0, stream>>>(x, pos, emb, h, hb);
  if (bigws)
    wconvert<<<dim3(256, 6, L_), 256, 0, stream>>>(Wq, Wk, Wv, Wo, W1, W2,
                                                   wt, 0, WT_LAYER);
  for (int l = 0; l < L_; l++) {
    u16* wtl = bigws ? wt + (size_t)l * WT_LAYER : wt;
    if (!bigws)
      wconvert<<<dim3(256, 6, 1), 256, 0, stream>>>(Wq, Wk, Wv, Wo, W1, W2,
                                                    wtl, l, 0);
    gemm_bk<4><<<dim3(24, 4), 1024, 0, stream>>>(
        hb, wtl, bq + l * HID_, bk + l * HID_, bv + l * HID_,
        qkv, nullptr, 1536, 512, 0);
    state_kernel<<<B_ * H_, 256, 0, stream>>>(
        S + (size_t)l * B_ * H_ * D_ * D_, Z + (size_t)l * B_ * H_ * D_, qkv,
        out_S + (size_t)l * B_ * H_ * D_ * D_, out_Z + (size_t)l * B_ * H_ * D_,
        attnb);
    gemm_bk<4><<<dim3(8, 4), 1024, 0, stream>>>(
        attnb, wtl + 786432, bo + l * HID_, nullptr, nullptr,
        tmpA, nullptr, 512, 512, 1);
    ln_kernel<<<B_, 256, 0, stream>>>(tmpA, h, ln1_g + l * HID_, ln1_b + l * HID_, h, hb);
    gemm_bk<4><<<dim3(32, 4), 1024, 0, stream>>>(
        hb, wtl + 1048576, b1 + l * FF_, nullptr, nullptr,
        nullptr, ff1, 2048, 512, 2);
    gemm_bk<16><<<dim3(8, 4), 1024, 0, stream>>>(
        ff1, wtl + 2097152, b2 + l * HID_, nullptr, nullptr,
        tmpB, nullptr, 512, 2048, 1);
    ln_kernel<<<B_, 256, 0, stream>>>(tmpB, h, ln2_g + l * HID_, ln2_b + l * HID_, h, hb);
  }
  ln_kernel<<<B_, 256, 0, stream>>>(h, nullptr, lnf_g, lnf_b, out_h, nullptr);
}